// Round 1
// baseline (268.293 us; speedup 1.0000x reference)
//
#include <hip/hip_runtime.h>
#include <hip/hip_bf16.h>

#define NT 4096
#define HD 2048
#define NE 16
#define ID 512
#define TWO_I 1024
#define PITCH 72   // LDS row pitch in ushorts (144B = 36 words -> bank stride 4, 2-way max on b128)

typedef __attribute__((ext_vector_type(8))) short bf16x8_t;
typedef __attribute__((ext_vector_type(4))) float f32x4_t;

__device__ __forceinline__ unsigned short f2bf(float f) {
  union { float f; unsigned int u; } v; v.f = f;
  unsigned int r = v.u + 0x7fffu + ((v.u >> 16) & 1u);
  return (unsigned short)(r >> 16);
}

// ---------------- cast x (f32 -> bf16), 8 elems/thread ----------------
__global__ void k_cast_x(const float* __restrict__ x, unsigned short* __restrict__ xb) {
  size_t i = ((size_t)blockIdx.x * 256 + threadIdx.x) * 8;
  float4 a = *(const float4*)(x + i);
  float4 b = *(const float4*)(x + i + 4);
  unsigned int w0 = (unsigned)f2bf(a.x) | ((unsigned)f2bf(a.y) << 16);
  unsigned int w1 = (unsigned)f2bf(a.z) | ((unsigned)f2bf(a.w) << 16);
  unsigned int w2 = (unsigned)f2bf(b.x) | ((unsigned)f2bf(b.y) << 16);
  unsigned int w3 = (unsigned)f2bf(b.z) | ((unsigned)f2bf(b.w) << 16);
  uint4 pk; pk.x = w0; pk.y = w1; pk.z = w2; pk.w = w3;
  *(uint4*)(xb + i) = pk;
}

// ---------------- routing: logits = onehot(base)*10 + mu @ Wr^T, argmax ----------------
__global__ void k_route(const float* __restrict__ mu, const int* __restrict__ tok,
                        const float* __restrict__ wr, int* __restrict__ eid) {
  int t = blockIdx.x;
  int tid = threadIdx.x;
  float p[NE];
#pragma unroll
  for (int e = 0; e < NE; ++e) p[e] = 0.f;
  const float* m = mu + (size_t)t * HD;
  for (int h = tid; h < HD; h += 256) {
    float mv = m[h];
#pragma unroll
    for (int e = 0; e < NE; ++e) p[e] += mv * wr[e * HD + h];
  }
#pragma unroll
  for (int e = 0; e < NE; ++e) {
    float v = p[e];
#pragma unroll
    for (int s = 32; s; s >>= 1) v += __shfl_xor(v, s, 64);
    p[e] = v;
  }
  __shared__ float red[4][NE];
  int lane = tid & 63, wv = tid >> 6;
  if (lane == 0) {
#pragma unroll
    for (int e = 0; e < NE; ++e) red[wv][e] = p[e];
  }
  __syncthreads();
  if (tid == 0) {
    int tk = tok[t];
    if (tk < 0) tk = 0;
    if (tk > 31999) tk = 31999;
    int base = tk & 15;  // 32000 % 16 == 0 so clip+mod == &15
    float best = -3.0e38f; int bi = 0;
    for (int e = 0; e < NE; ++e) {
      float v = red[0][e] + red[1][e] + red[2][e] + red[3][e];
      if (e == base) v += 10.0f;
      if (v > best) { best = v; bi = e; }
    }
    eid[t] = bi;
  }
}

// ---------------- bucket tokens by expert ----------------
__global__ void k_init(int* counts, int* cursors) {
  int i = threadIdx.x;
  if (i < NE) { counts[i] = 0; cursors[i] = 0; }
}
__global__ void k_hist(const int* __restrict__ eid, int* __restrict__ counts) {
  int t = blockIdx.x * 256 + threadIdx.x;
  if (t < NT) atomicAdd(&counts[eid[t]], 1);
}
__global__ void k_scan(const int* __restrict__ counts, int* __restrict__ offsets,
                       int* __restrict__ cursors) {
  if (threadIdx.x == 0) {
    int s = 0;
    for (int e = 0; e < NE; ++e) { offsets[e] = s; cursors[e] = s; s += counts[e]; }
    offsets[NE] = s;
  }
}
__global__ void k_scatter(const int* __restrict__ eid, int* __restrict__ cursors,
                          int* __restrict__ tlist) {
  int t = blockIdx.x * 256 + threadIdx.x;
  if (t < NT) {
    int e = eid[t];
    int pos = atomicAdd(&cursors[e], 1);
    tlist[pos] = t;
  }
}

// ---------------- gemm1: h = silu(x@Wg) * (x@Wu), per expert ----------------
// grid (8 col-tiles of 64 h-cols, 32 max token-tiles of 128, 16 experts), 256 thr
__global__ __launch_bounds__(256, 2) void k_gemm1(
    const unsigned short* __restrict__ xb, const float* __restrict__ gup,
    const int* __restrict__ offsets, const int* __restrict__ tlist,
    unsigned short* __restrict__ hbuf) {
  int e = blockIdx.z;
  int off = offsets[e], cnt = offsets[e + 1] - off;
  int tb = blockIdx.y * 128;
  if (tb >= cnt) return;
  int c0 = blockIdx.x * 64;

  __shared__ unsigned short lA[128 * PITCH];  // [token][k]
  __shared__ unsigned short lB[128 * PITCH];  // [col][k]; cols 0-63 gate, 64-127 up
  __shared__ int ltok[128];

  int tid = threadIdx.x, lane = tid & 63, wv = tid >> 6;
  if (tid < 128) {
    int r = tb + tid; if (r > cnt - 1) r = cnt - 1;
    ltok[tid] = tlist[off + r];
  }
  __syncthreads();

  f32x4_t zero = {0.f, 0.f, 0.f, 0.f};
  f32x4_t accg[2][4], accu[2][4];
#pragma unroll
  for (int m = 0; m < 2; ++m)
#pragma unroll
    for (int n = 0; n < 4; ++n) { accg[m][n] = zero; accu[m][n] = zero; }

  const float* Wg = gup + (size_t)e * HD * TWO_I;

  for (int k0 = 0; k0 < HD; k0 += 64) {
    // stage A: 128 rows x 64 k, 16B per item
#pragma unroll
    for (int it = 0; it < 4; ++it) {
      int id = tid + 256 * it;
      int row = id >> 3, oct = id & 7;
      const unsigned short* src = xb + (size_t)ltok[row] * HD + k0 + oct * 8;
      *(uint4*)&lA[row * PITCH + oct * 8] = *(const uint4*)src;
    }
    // stage B transposed: read 8 k-strided f32 (lane-coalesced along col), pack bf16
#pragma unroll
    for (int it = 0; it < 4; ++it) {
      int id = tid + 256 * it;
      int col = id & 127, koct = id >> 7;
      int gcol = (col < 64) ? (c0 + col) : (ID + c0 + (col - 64));
      const float* src = Wg + (size_t)(k0 + koct * 8) * TWO_I + gcol;
      unsigned int w0 = (unsigned)f2bf(src[0]) | ((unsigned)f2bf(src[(size_t)TWO_I]) << 16);
      unsigned int w1 = (unsigned)f2bf(src[(size_t)2 * TWO_I]) | ((unsigned)f2bf(src[(size_t)3 * TWO_I]) << 16);
      unsigned int w2 = (unsigned)f2bf(src[(size_t)4 * TWO_I]) | ((unsigned)f2bf(src[(size_t)5 * TWO_I]) << 16);
      unsigned int w3 = (unsigned)f2bf(src[(size_t)6 * TWO_I]) | ((unsigned)f2bf(src[(size_t)7 * TWO_I]) << 16);
      uint4 pk; pk.x = w0; pk.y = w1; pk.z = w2; pk.w = w3;
      *(uint4*)&lB[col * PITCH + koct * 8] = pk;
    }
    __syncthreads();

    int mb = wv * 32, lr = lane & 15;
#pragma unroll
    for (int kk = 0; kk < 2; ++kk) {
      int klo = kk * 32 + 8 * (lane >> 4);
      bf16x8_t a[2], bg[4], bu[4];
#pragma unroll
      for (int m = 0; m < 2; ++m) a[m] = *(bf16x8_t*)&lA[(mb + m * 16 + lr) * PITCH + klo];
#pragma unroll
      for (int n = 0; n < 4; ++n) {
        bg[n] = *(bf16x8_t*)&lB[(n * 16 + lr) * PITCH + klo];
        bu[n] = *(bf16x8_t*)&lB[((64 + n * 16) + lr) * PITCH + klo];
      }
#pragma unroll
      for (int m = 0; m < 2; ++m)
#pragma unroll
        for (int n = 0; n < 4; ++n) {
          accg[m][n] = __builtin_amdgcn_mfma_f32_16x16x32_bf16(a[m], bg[n], accg[m][n], 0, 0, 0);
          accu[m][n] = __builtin_amdgcn_mfma_f32_16x16x32_bf16(a[m], bu[n], accu[m][n], 0, 0, 0);
        }
    }
    __syncthreads();
  }

  // epilogue: h = silu(g)*u -> bf16, rows sorted by expert slot
  int mb = wv * 32, lr = lane & 15, rq = (lane >> 4) * 4;
#pragma unroll
  for (int m = 0; m < 2; ++m)
#pragma unroll
    for (int n = 0; n < 4; ++n)
#pragma unroll
      for (int j = 0; j < 4; ++j) {
        int r = tb + mb + m * 16 + rq + j;
        if (r < cnt) {
          float g = accg[m][n][j], u = accu[m][n][j];
          float hv = (g / (1.f + __expf(-g))) * u;
          hbuf[(size_t)(off + r) * ID + c0 + n * 16 + lr] = f2bf(hv);
        }
      }
}

// ---------------- gemm2: out = h @ Wd, per expert ----------------
// grid (16 col-tiles of 128, 32 max token-tiles of 128, 16 experts), 256 thr
__global__ __launch_bounds__(256, 2) void k_gemm2(
    const unsigned short* __restrict__ hbuf, const float* __restrict__ dwn,
    const int* __restrict__ offsets, const int* __restrict__ tlist,
    float* __restrict__ out) {
  int e = blockIdx.z;
  int off = offsets[e], cnt = offsets[e + 1] - off;
  int tb = blockIdx.y * 128;
  if (tb >= cnt) return;
  int c0 = blockIdx.x * 128;

  __shared__ unsigned short lA[128 * PITCH];
  __shared__ unsigned short lB[128 * PITCH];

  int tid = threadIdx.x, lane = tid & 63, wv = tid >> 6;
  f32x4_t zero = {0.f, 0.f, 0.f, 0.f};
  f32x4_t acc[2][8];
#pragma unroll
  for (int m = 0; m < 2; ++m)
#pragma unroll
    for (int n = 0; n < 8; ++n) acc[m][n] = zero;

  const float* Wd = dwn + (size_t)e * ID * HD;

  for (int k0 = 0; k0 < ID; k0 += 64) {
#pragma unroll
    for (int it = 0; it < 4; ++it) {
      int id = tid + 256 * it;
      int row = id >> 3, oct = id & 7;
      int r = tb + row; if (r > cnt - 1) r = cnt - 1;
      const unsigned short* src = hbuf + (size_t)(off + r) * ID + k0 + oct * 8;
      *(uint4*)&lA[row * PITCH + oct * 8] = *(const uint4*)src;
    }
#pragma unroll
    for (int it = 0; it < 4; ++it) {
      int id = tid + 256 * it;
      int col = id & 127, koct = id >> 7;
      const float* src = Wd + (size_t)(k0 + koct * 8) * HD + c0 + col;
      unsigned int w0 = (unsigned)f2bf(src[0]) | ((unsigned)f2bf(src[(size_t)HD]) << 16);
      unsigned int w1 = (unsigned)f2bf(src[(size_t)2 * HD]) | ((unsigned)f2bf(src[(size_t)3 * HD]) << 16);
      unsigned int w2 = (unsigned)f2bf(src[(size_t)4 * HD]) | ((unsigned)f2bf(src[(size_t)5 * HD]) << 16);
      unsigned int w3 = (unsigned)f2bf(src[(size_t)6 * HD]) | ((unsigned)f2bf(src[(size_t)7 * HD]) << 16);
      uint4 pk; pk.x = w0; pk.y = w1; pk.z = w2; pk.w = w3;
      *(uint4*)&lB[col * PITCH + koct * 8] = pk;
    }
    __syncthreads();

    int mb = wv * 32, lr = lane & 15;
#pragma unroll
    for (int kk = 0; kk < 2; ++kk) {
      int klo = kk * 32 + 8 * (lane >> 4);
      bf16x8_t a[2], b[8];
#pragma unroll
      for (int m = 0; m < 2; ++m) a[m] = *(bf16x8_t*)&lA[(mb + m * 16 + lr) * PITCH + klo];
#pragma unroll
      for (int n = 0; n < 8; ++n) b[n] = *(bf16x8_t*)&lB[(n * 16 + lr) * PITCH + klo];
#pragma unroll
      for (int m = 0; m < 2; ++m)
#pragma unroll
        for (int n = 0; n < 8; ++n)
          acc[m][n] = __builtin_amdgcn_mfma_f32_16x16x32_bf16(a[m], b[n], acc[m][n], 0, 0, 0);
    }
    __syncthreads();
  }

  int mb = wv * 32, lr = lane & 15, rq = (lane >> 4) * 4;
#pragma unroll
  for (int m = 0; m < 2; ++m)
#pragma unroll
    for (int n = 0; n < 8; ++n)
#pragma unroll
      for (int j = 0; j < 4; ++j) {
        int r = tb + mb + m * 16 + rq + j;
        if (r < cnt) {
          out[(size_t)tlist[off + r] * HD + c0 + n * 16 + lr] = acc[m][n][j];
        }
      }
}

extern "C" void kernel_launch(void* const* d_in, const int* in_sizes, int n_in,
                              void* d_out, int out_size, void* d_ws, size_t ws_size,
                              hipStream_t stream) {
  (void)in_sizes; (void)n_in; (void)out_size; (void)ws_size;
  const float* x   = (const float*)d_in[0];
  const int*   tok = (const int*)d_in[1];
  const float* mu  = (const float*)d_in[2];
  const float* gup = (const float*)d_in[3];
  const float* dwn = (const float*)d_in[4];
  const float* wr  = (const float*)d_in[5];
  float* out = (float*)d_out;

  char* ws = (char*)d_ws;
  int* eid     = (int*)ws;                 // 4096 ints
  int* tlist   = (int*)(ws + 16384);       // 4096 ints
  int* counts  = (int*)(ws + 32768);       // 16
  int* offsets = (int*)(ws + 32896);       // 17
  int* cursors = (int*)(ws + 33024);       // 16
  unsigned short* xb   = (unsigned short*)(ws + 65536);                       // 16 MB
  unsigned short* hbuf = (unsigned short*)(ws + 65536 + (size_t)NT * HD * 2); // 4 MB

  k_cast_x <<<4096, 256, 0, stream>>>(x, xb);
  k_route  <<<NT, 256, 0, stream>>>(mu, tok, wr, eid);
  k_init   <<<1, 64, 0, stream>>>(counts, cursors);
  k_hist   <<<16, 256, 0, stream>>>(eid, counts);
  k_scan   <<<1, 64, 0, stream>>>(counts, offsets, cursors);
  k_scatter<<<16, 256, 0, stream>>>(eid, cursors, tlist);
  k_gemm1  <<<dim3(8, 32, 16), 256, 0, stream>>>(xb, gup, offsets, tlist, hbuf);
  k_gemm2  <<<dim3(16, 32, 16), 256, 0, stream>>>(hbuf, dwn, offsets, tlist, out);
}

// Round 2
// 244.734 us; speedup vs baseline: 1.0963x; 1.0963x over previous
//
#include <hip/hip_runtime.h>
#include <hip/hip_bf16.h>

#define NT 4096
#define HD 2048
#define NE 16
#define ID 512
#define TWO_I 1024
#define PITCH 72   // LDS row pitch in ushorts (144B) -> dodges pow2 bank stride
#define MAXITEMS 47  // worst case: ceil(4081/128)=32 + 15 singleton experts

typedef __attribute__((ext_vector_type(8))) short bf16x8_t;
typedef __attribute__((ext_vector_type(4))) float f32x4_t;

__device__ __forceinline__ unsigned short f2bf(float f) {
  union { float f; unsigned int u; } v; v.f = f;
  unsigned int r = v.u + 0x7fffu + ((v.u >> 16) & 1u);
  return (unsigned short)(r >> 16);
}

// ---------------- cast x (f32 -> bf16), 8 elems/thread ----------------
__global__ void k_cast_x(const float* __restrict__ x, unsigned short* __restrict__ xb) {
  size_t i = ((size_t)blockIdx.x * 256 + threadIdx.x) * 8;
  float4 a = *(const float4*)(x + i);
  float4 b = *(const float4*)(x + i + 4);
  unsigned int w0 = (unsigned)f2bf(a.x) | ((unsigned)f2bf(a.y) << 16);
  unsigned int w1 = (unsigned)f2bf(a.z) | ((unsigned)f2bf(a.w) << 16);
  unsigned int w2 = (unsigned)f2bf(b.x) | ((unsigned)f2bf(b.y) << 16);
  unsigned int w3 = (unsigned)f2bf(b.z) | ((unsigned)f2bf(b.w) << 16);
  uint4 pk; pk.x = w0; pk.y = w1; pk.z = w2; pk.w = w3;
  *(uint4*)(xb + i) = pk;
}

// ---------------- routing ----------------
__global__ void k_route(const float* __restrict__ mu, const int* __restrict__ tok,
                        const float* __restrict__ wr, int* __restrict__ eid) {
  int t = blockIdx.x;
  int tid = threadIdx.x;
  float p[NE];
#pragma unroll
  for (int e = 0; e < NE; ++e) p[e] = 0.f;
  const float* m = mu + (size_t)t * HD;
  for (int h = tid; h < HD; h += 256) {
    float mv = m[h];
#pragma unroll
    for (int e = 0; e < NE; ++e) p[e] += mv * wr[e * HD + h];
  }
#pragma unroll
  for (int e = 0; e < NE; ++e) {
    float v = p[e];
#pragma unroll
    for (int s = 32; s; s >>= 1) v += __shfl_xor(v, s, 64);
    p[e] = v;
  }
  __shared__ float red[4][NE];
  int lane = tid & 63, wv = tid >> 6;
  if (lane == 0) {
#pragma unroll
    for (int e = 0; e < NE; ++e) red[wv][e] = p[e];
  }
  __syncthreads();
  if (tid == 0) {
    int tk = tok[t];
    if (tk < 0) tk = 0;
    if (tk > 31999) tk = 31999;
    int base = tk & 15;
    float best = -3.0e38f; int bi = 0;
    for (int e = 0; e < NE; ++e) {
      float v = red[0][e] + red[1][e] + red[2][e] + red[3][e];
      if (e == base) v += 10.0f;
      if (v > best) { best = v; bi = e; }
    }
    eid[t] = bi;
  }
}

// ---------------- bucket tokens by expert + build compacted worklist ----------------
__global__ void k_init(int* counts, int* cursors) {
  int i = threadIdx.x;
  if (i < NE) { counts[i] = 0; cursors[i] = 0; }
}
__global__ void k_hist(const int* __restrict__ eid, int* __restrict__ counts) {
  int t = blockIdx.x * 256 + threadIdx.x;
  if (t < NT) atomicAdd(&counts[eid[t]], 1);
}
__global__ void k_scan(const int* __restrict__ counts, int* __restrict__ offsets,
                       int* __restrict__ cursors, int* __restrict__ wk) {
  if (threadIdx.x == 0) {
    int s = 0;
    for (int e = 0; e < NE; ++e) { offsets[e] = s; cursors[e] = s; s += counts[e]; }
    offsets[NE] = s;
    // worklist: (expert, mtile) pairs packed e | (m<<8); count in wk[MAXITEMS]
    int n = 0;
    for (int e = 0; e < NE; ++e) {
      int tiles = (counts[e] + 127) >> 7;
      for (int m = 0; m < tiles; ++m) { wk[n++] = e | (m << 8); }
    }
    wk[MAXITEMS] = n;
  }
}
__global__ void k_scatter(const int* __restrict__ eid, int* __restrict__ cursors,
                          int* __restrict__ tlist) {
  int t = blockIdx.x * 256 + threadIdx.x;
  if (t < NT) {
    int e = eid[t];
    int pos = atomicAdd(&cursors[e], 1);
    tlist[pos] = t;
  }
}

// ---------------- gemm1: h = silu(x@Wg) * (x@Wu), per worklist item ----------------
// grid (8 col-tiles of 64 h-cols, MAXITEMS), 256 thr
__global__ __launch_bounds__(256, 4) void k_gemm1(
    const unsigned short* __restrict__ xb, const float* __restrict__ gup,
    const int* __restrict__ offsets, const int* __restrict__ tlist,
    const int* __restrict__ wk, unsigned short* __restrict__ hbuf) {
  int item = blockIdx.y;
  if (item >= wk[MAXITEMS]) return;
  int w = wk[item];
  int e = w & 255, tb = (w >> 8) * 128;
  int off = offsets[e], cnt = offsets[e + 1] - off;
  int c0 = blockIdx.x * 64;

  __shared__ unsigned short lA[128 * PITCH];  // [token][k]
  __shared__ unsigned short lB[128 * PITCH];  // [col][k]; cols 0-63 gate, 64-127 up
  __shared__ int ltok[128];

  int tid = threadIdx.x, lane = tid & 63, wv = tid >> 6;
  if (tid < 128) {
    int r = tb + tid; if (r > cnt - 1) r = cnt - 1;
    ltok[tid] = tlist[off + r];
  }
  __syncthreads();

  f32x4_t zero = {0.f, 0.f, 0.f, 0.f};
  f32x4_t accg[2][4], accu[2][4];
#pragma unroll
  for (int m = 0; m < 2; ++m)
#pragma unroll
    for (int n = 0; n < 4; ++n) { accg[m][n] = zero; accu[m][n] = zero; }

  const float* Wg = gup + (size_t)e * HD * TWO_I;

  for (int k0 = 0; k0 < HD; k0 += 64) {
#pragma unroll
    for (int it = 0; it < 4; ++it) {
      int id = tid + 256 * it;
      int row = id >> 3, oct = id & 7;
      const unsigned short* src = xb + (size_t)ltok[row] * HD + k0 + oct * 8;
      *(uint4*)&lA[row * PITCH + oct * 8] = *(const uint4*)src;
    }
#pragma unroll
    for (int it = 0; it < 4; ++it) {
      int id = tid + 256 * it;
      int col = id & 127, koct = id >> 7;
      int gcol = (col < 64) ? (c0 + col) : (ID + c0 + (col - 64));
      const float* src = Wg + (size_t)(k0 + koct * 8) * TWO_I + gcol;
      unsigned int w0 = (unsigned)f2bf(src[0]) | ((unsigned)f2bf(src[(size_t)TWO_I]) << 16);
      unsigned int w1 = (unsigned)f2bf(src[(size_t)2 * TWO_I]) | ((unsigned)f2bf(src[(size_t)3 * TWO_I]) << 16);
      unsigned int w2 = (unsigned)f2bf(src[(size_t)4 * TWO_I]) | ((unsigned)f2bf(src[(size_t)5 * TWO_I]) << 16);
      unsigned int w3 = (unsigned)f2bf(src[(size_t)6 * TWO_I]) | ((unsigned)f2bf(src[(size_t)7 * TWO_I]) << 16);
      uint4 pk; pk.x = w0; pk.y = w1; pk.z = w2; pk.w = w3;
      *(uint4*)&lB[col * PITCH + koct * 8] = pk;
    }
    __syncthreads();

    int mb = wv * 32, lr = lane & 15;
#pragma unroll
    for (int kk = 0; kk < 2; ++kk) {
      int klo = kk * 32 + 8 * (lane >> 4);
      bf16x8_t a[2], bg[4], bu[4];
#pragma unroll
      for (int m = 0; m < 2; ++m) a[m] = *(bf16x8_t*)&lA[(mb + m * 16 + lr) * PITCH + klo];
#pragma unroll
      for (int n = 0; n < 4; ++n) {
        bg[n] = *(bf16x8_t*)&lB[(n * 16 + lr) * PITCH + klo];
        bu[n] = *(bf16x8_t*)&lB[((64 + n * 16) + lr) * PITCH + klo];
      }
#pragma unroll
      for (int m = 0; m < 2; ++m)
#pragma unroll
        for (int n = 0; n < 4; ++n) {
          accg[m][n] = __builtin_amdgcn_mfma_f32_16x16x32_bf16(a[m], bg[n], accg[m][n], 0, 0, 0);
          accu[m][n] = __builtin_amdgcn_mfma_f32_16x16x32_bf16(a[m], bu[n], accu[m][n], 0, 0, 0);
        }
    }
    __syncthreads();
  }

  int mb = wv * 32, lr = lane & 15, rq = (lane >> 4) * 4;
#pragma unroll
  for (int m = 0; m < 2; ++m)
#pragma unroll
    for (int n = 0; n < 4; ++n)
#pragma unroll
      for (int j = 0; j < 4; ++j) {
        int r = tb + mb + m * 16 + rq + j;
        if (r < cnt) {
          float g = accg[m][n][j], u = accu[m][n][j];
          float hv = (g / (1.f + __expf(-g))) * u;
          hbuf[(size_t)(off + r) * ID + c0 + n * 16 + lr] = f2bf(hv);
        }
      }
}

// ---------------- gemm2: out = h @ Wd, per worklist item ----------------
// grid (16 col-tiles of 128, MAXITEMS), 256 thr
__global__ __launch_bounds__(256, 4) void k_gemm2(
    const unsigned short* __restrict__ hbuf, const float* __restrict__ dwn,
    const int* __restrict__ offsets, const int* __restrict__ tlist,
    const int* __restrict__ wk, float* __restrict__ out) {
  int item = blockIdx.y;
  if (item >= wk[MAXITEMS]) return;
  int w = wk[item];
  int e = w & 255, tb = (w >> 8) * 128;
  int off = offsets[e], cnt = offsets[e + 1] - off;
  int c0 = blockIdx.x * 128;

  __shared__ unsigned short lA[128 * PITCH];
  __shared__ unsigned short lB[128 * PITCH];

  int tid = threadIdx.x, lane = tid & 63, wv = tid >> 6;
  f32x4_t zero = {0.f, 0.f, 0.f, 0.f};
  f32x4_t acc[2][8];
#pragma unroll
  for (int m = 0; m < 2; ++m)
#pragma unroll
    for (int n = 0; n < 8; ++n) acc[m][n] = zero;

  const float* Wd = dwn + (size_t)e * ID * HD;

  for (int k0 = 0; k0 < ID; k0 += 64) {
#pragma unroll
    for (int it = 0; it < 4; ++it) {
      int id = tid + 256 * it;
      int row = id >> 3, oct = id & 7;
      int r = tb + row; if (r > cnt - 1) r = cnt - 1;
      const unsigned short* src = hbuf + (size_t)(off + r) * ID + k0 + oct * 8;
      *(uint4*)&lA[row * PITCH + oct * 8] = *(const uint4*)src;
    }
#pragma unroll
    for (int it = 0; it < 4; ++it) {
      int id = tid + 256 * it;
      int col = id & 127, koct = id >> 7;
      const float* src = Wd + (size_t)(k0 + koct * 8) * HD + c0 + col;
      unsigned int w0 = (unsigned)f2bf(src[0]) | ((unsigned)f2bf(src[(size_t)HD]) << 16);
      unsigned int w1 = (unsigned)f2bf(src[(size_t)2 * HD]) | ((unsigned)f2bf(src[(size_t)3 * HD]) << 16);
      unsigned int w2 = (unsigned)f2bf(src[(size_t)4 * HD]) | ((unsigned)f2bf(src[(size_t)5 * HD]) << 16);
      unsigned int w3 = (unsigned)f2bf(src[(size_t)6 * HD]) | ((unsigned)f2bf(src[(size_t)7 * HD]) << 16);
      uint4 pk; pk.x = w0; pk.y = w1; pk.z = w2; pk.w = w3;
      *(uint4*)&lB[col * PITCH + koct * 8] = pk;
    }
    __syncthreads();

    int mb = wv * 32, lr = lane & 15;
#pragma unroll
    for (int kk = 0; kk < 2; ++kk) {
      int klo = kk * 32 + 8 * (lane >> 4);
      bf16x8_t a[2], b[8];
#pragma unroll
      for (int m = 0; m < 2; ++m) a[m] = *(bf16x8_t*)&lA[(mb + m * 16 + lr) * PITCH + klo];
#pragma unroll
      for (int n = 0; n < 8; ++n) b[n] = *(bf16x8_t*)&lB[(n * 16 + lr) * PITCH + klo];
#pragma unroll
      for (int m = 0; m < 2; ++m)
#pragma unroll
        for (int n = 0; n < 8; ++n)
          acc[m][n] = __builtin_amdgcn_mfma_f32_16x16x32_bf16(a[m], b[n], acc[m][n], 0, 0, 0);
    }
    __syncthreads();
  }

  int mb = wv * 32, lr = lane & 15, rq = (lane >> 4) * 4;
#pragma unroll
  for (int m = 0; m < 2; ++m)
#pragma unroll
    for (int n = 0; n < 8; ++n)
#pragma unroll
      for (int j = 0; j < 4; ++j) {
        int r = tb + mb + m * 16 + rq + j;
        if (r < cnt) {
          out[(size_t)tlist[off + r] * HD + c0 + n * 16 + lr] = acc[m][n][j];
        }
      }
}

extern "C" void kernel_launch(void* const* d_in, const int* in_sizes, int n_in,
                              void* d_out, int out_size, void* d_ws, size_t ws_size,
                              hipStream_t stream) {
  (void)in_sizes; (void)n_in; (void)out_size; (void)ws_size;
  const float* x   = (const float*)d_in[0];
  const int*   tok = (const int*)d_in[1];
  const float* mu  = (const float*)d_in[2];
  const float* gup = (const float*)d_in[3];
  const float* dwn = (const float*)d_in[4];
  const float* wr  = (const float*)d_in[5];
  float* out = (float*)d_out;

  char* ws = (char*)d_ws;
  int* eid     = (int*)ws;                 // 4096 ints
  int* tlist   = (int*)(ws + 16384);       // 4096 ints
  int* counts  = (int*)(ws + 32768);       // 16
  int* offsets = (int*)(ws + 32896);       // 17
  int* cursors = (int*)(ws + 33024);       // 16
  int* wk      = (int*)(ws + 33152);       // MAXITEMS+1
  unsigned short* xb   = (unsigned short*)(ws + 65536);                       // 16 MB
  unsigned short* hbuf = (unsigned short*)(ws + 65536 + (size_t)NT * HD * 2); // 4 MB

  k_cast_x <<<4096, 256, 0, stream>>>(x, xb);
  k_route  <<<NT, 256, 0, stream>>>(mu, tok, wr, eid);
  k_init   <<<1, 64, 0, stream>>>(counts, cursors);
  k_hist   <<<16, 256, 0, stream>>>(eid, counts);
  k_scan   <<<1, 64, 0, stream>>>(counts, offsets, cursors, wk);
  k_scatter<<<16, 256, 0, stream>>>(eid, cursors, tlist);
  k_gemm1  <<<dim3(8, MAXITEMS), 256, 0, stream>>>(xb, gup, offsets, tlist, wk, hbuf);
  k_gemm2  <<<dim3(16, MAXITEMS), 256, 0, stream>>>(hbuf, dwn, offsets, tlist, wk, out);
}